// Round 3
// baseline (495.631 us; speedup 1.0000x reference)
//
#include <hip/hip_runtime.h>

#define T_TOK  2048
#define DIMD   1024
#define INTERI 512
#define NEXP   16
#define NSEG   17   // 16 routed + 1 shared (index 16)

typedef __bf16 bf16x8 __attribute__((ext_vector_type(8)));
typedef float  f32x4  __attribute__((ext_vector_type(4)));

// ---------- helpers ----------
__device__ __forceinline__ unsigned short f2b(float f) {
    union { float f; unsigned int u; } c; c.f = f;
    unsigned int u = c.u;
    unsigned int r = (u + 0x7FFFu + ((u >> 16) & 1u)) >> 16;  // RNE
    return (unsigned short)r;
}

__device__ __forceinline__ void cp16(const unsigned short* g, unsigned short* l) {
    // direct global->LDS, 16B per lane; LDS dest = wave-uniform base + lane*16
    __builtin_amdgcn_global_load_lds(
        (const __attribute__((address_space(1))) unsigned int*)g,
        (__attribute__((address_space(3))) unsigned int*)l,
        16, 0, 0);
}

// ---------- fp32 -> bf16 conversion, all 7 tensors in one launch ----------
__global__ __launch_bounds__(256) void cvt_all_kernel(
    const float* __restrict__ x,  const float* __restrict__ w1,
    const float* __restrict__ w3, const float* __restrict__ w2,
    const float* __restrict__ ws1, const float* __restrict__ ws3,
    const float* __restrict__ ws2,
    unsigned short* __restrict__ xb,  unsigned short* __restrict__ w1b,
    unsigned short* __restrict__ w3b, unsigned short* __restrict__ w2b,
    unsigned short* __restrict__ ws1b, unsigned short* __restrict__ ws3b,
    unsigned short* __restrict__ ws2b)
{
    int g = blockIdx.x * 256 + threadIdx.x;
    const float* s; unsigned short* d; int i;
    if      (g < 524288)  { s = x;   d = xb;   i = g; }
    else if (g < 2621440) { s = w1;  d = w1b;  i = g - 524288; }
    else if (g < 4718592) { s = w3;  d = w3b;  i = g - 2621440; }
    else if (g < 6815744) { s = w2;  d = w2b;  i = g - 4718592; }
    else if (g < 6946816) { s = ws1; d = ws1b; i = g - 6815744; }
    else if (g < 7077888) { s = ws3; d = ws3b; i = g - 6946816; }
    else                  { s = ws2; d = ws2b; i = g - 7077888; }
    float4 v = ((const float4*)s)[i];
    ushort4 o;
    o.x = f2b(v.x); o.y = f2b(v.y); o.z = f2b(v.z); o.w = f2b(v.w);
    ((ushort4*)d)[i] = o;
}

// ---------- gate ----------
__global__ __launch_bounds__(256) void gate_kernel(
    const float* __restrict__ x, const float* __restrict__ gw,
    const float* __restrict__ gb,
    int* __restrict__ counts, int* __restrict__ lst, float* __restrict__ lstw)
{
    int tok  = blockIdx.x * 4 + (threadIdx.x >> 6);   // one wave per token
    int lane = threadIdx.x & 63;
    const float* xp = x + (size_t)tok * DIMD;
    float xv[16];
#pragma unroll
    for (int j = 0; j < 16; ++j) xv[j] = xp[j * 64 + lane];

    float sc[16];
#pragma unroll
    for (int e = 0; e < 16; ++e) {
        const float* gwe = gw + e * DIMD;
        float p = 0.f;
#pragma unroll
        for (int j = 0; j < 16; ++j) p += xv[j] * gwe[j * 64 + lane];
#pragma unroll
        for (int o = 32; o; o >>= 1) p += __shfl_xor(p, o, 64);
        sc[e] = p;
    }
    if (lane != 0) return;

    float orig[16], s[16];
#pragma unroll
    for (int e = 0; e < 16; ++e) {
        orig[e] = 1.f / (1.f + expf(-sc[e]));
        s[e] = orig[e] + gb[e];
    }
    float gmax[4];
#pragma unroll
    for (int g = 0; g < 4; ++g) {
        float m = s[4 * g];
        for (int j = 1; j < 4; ++j) m = fmaxf(m, s[4 * g + j]);
        gmax[g] = m;
    }
    int g0 = 0;
    for (int g = 1; g < 4; ++g) if (gmax[g] > gmax[g0]) g0 = g;
    int g1 = -1;
    for (int g = 0; g < 4; ++g) { if (g == g0) continue; if (g1 < 0 || gmax[g] > gmax[g1]) g1 = g; }
    unsigned keep = (0xFu << (4 * g0)) | (0xFu << (4 * g1));
    unsigned used = 0;
    for (int j = 0; j < 4; ++j) {
        int best = -1;
        for (int e = 0; e < 16; ++e) {
            if (!((keep >> e) & 1u) || ((used >> e) & 1u)) continue;
            if (best < 0 || s[e] > s[best]) best = e;
        }
        used |= 1u << best;
        float w = orig[best];
        int pos = atomicAdd(&counts[best], 1);
        lst [best * T_TOK + pos] = tok;
        lstw[best * T_TOK + pos] = w;
    }
}

// ---------- GEMM1: H = silu(X W1^T) * (X W3^T), 128x64 tile, BK=64, pipelined ----------
// LDS per stage stored as two BK=32 panels (row pitch 64B -> conflict-free)
__global__ __launch_bounds__(256) void gemm1_kernel(
    const unsigned short* __restrict__ xb,
    const unsigned short* __restrict__ w1b,
    const unsigned short* __restrict__ w3b,
    const unsigned short* __restrict__ ws1b,
    const unsigned short* __restrict__ ws3b,
    const int* __restrict__ counts,
    const int* __restrict__ lst,
    unsigned short* __restrict__ H)
{
    const int e   = blockIdx.z;
    const int n_e = (e == NEXP) ? T_TOK : counts[e];
    const int m0  = blockIdx.x * 128;
    if (m0 >= n_e) return;
    const int n0  = blockIdx.y * 64;

    const unsigned short* w1p = (e == NEXP) ? ws1b : w1b + (size_t)e * INTERI * DIMD;
    const unsigned short* w3p = (e == NEXP) ? ws3b : w3b + (size_t)e * INTERI * DIMD;
    const int* lste = lst + e * T_TOK;

    // [buf][panel kk][row][32 elems]
    __shared__ __align__(16) unsigned short lA [2][2][128 * 32];  // 32 KB
    __shared__ __align__(16) unsigned short lB1[2][2][64 * 32];   // 16 KB
    __shared__ __align__(16) unsigned short lB3[2][2][64 * 32];   // 16 KB

    const int tid  = threadIdx.x;
    const int wave = tid >> 6;
    const int lane = tid & 63;
    const int r4   = tid >> 2;        // 0..63 (row within 64-row group)
    const int seg  = (tid & 3) * 8;   // k-elem offset within 32-panel

    // gathered tokens for A rows r4 and r4+64
    int tk[2];
#pragma unroll
    for (int h = 0; h < 2; ++h) {
        int r = m0 + r4 + h * 64;
        int rr = (r < n_e) ? r : m0;
        tk[h] = (e == NEXP) ? rr : lste[rr];
    }
    const unsigned short* gA0 = xb + (size_t)tk[0] * DIMD + seg;
    const unsigned short* gA1 = xb + (size_t)tk[1] * DIMD + seg;
    const unsigned short* gB1 = w1p + (size_t)(n0 + r4) * DIMD + seg;
    const unsigned short* gB3 = w3p + (size_t)(n0 + r4) * DIMD + seg;

    const int wbase = wave * 16 * 32;   // wave-uniform LDS element base (16 rows/wave)

    auto stage = [&](int k0, int b) {
#pragma unroll
        for (int kk = 0; kk < 2; ++kk) {
            cp16(gA0 + k0 + kk * 32, &lA [b][kk][wbase]);
            cp16(gA1 + k0 + kk * 32, &lA [b][kk][64 * 32 + wbase]);
            cp16(gB1 + k0 + kk * 32, &lB1[b][kk][wbase]);
            cp16(gB3 + k0 + kk * 32, &lB3[b][kk][wbase]);
        }
    };

    f32x4 acc1[4][2], acc3[4][2];
    const f32x4 zero = {0.f, 0.f, 0.f, 0.f};
#pragma unroll
    for (int i = 0; i < 4; ++i)
#pragma unroll
        for (int j = 0; j < 2; ++j) { acc1[i][j] = zero; acc3[i][j] = zero; }

    const int wr   = (wave >> 1) * 64;   // wave row offset (2 row-groups)
    const int wc   = (wave & 1) * 32;    // wave col offset
    const int quad = lane >> 4;
    const int lrow = lane & 15;

    stage(0, 0);
    __syncthreads();

    const int NK = DIMD / 64;  // 16
    for (int it = 0; it < NK; ++it) {
        const int b = it & 1;
        if (it + 1 < NK) stage((it + 1) * 64, b ^ 1);
#pragma unroll
        for (int kk = 0; kk < 2; ++kk) {
            bf16x8 a[4], b1v[2], b3v[2];
#pragma unroll
            for (int t = 0; t < 4; ++t)
                a[t] = *(const bf16x8*)&lA[b][kk][(wr + t * 16 + lrow) * 32 + quad * 8];
#pragma unroll
            for (int t = 0; t < 2; ++t) {
                b1v[t] = *(const bf16x8*)&lB1[b][kk][(wc + t * 16 + lrow) * 32 + quad * 8];
                b3v[t] = *(const bf16x8*)&lB3[b][kk][(wc + t * 16 + lrow) * 32 + quad * 8];
            }
#pragma unroll
            for (int i = 0; i < 4; ++i)
#pragma unroll
                for (int j = 0; j < 2; ++j) {
                    acc1[i][j] = __builtin_amdgcn_mfma_f32_16x16x32_bf16(a[i], b1v[j], acc1[i][j], 0, 0, 0);
                    acc3[i][j] = __builtin_amdgcn_mfma_f32_16x16x32_bf16(a[i], b3v[j], acc3[i][j], 0, 0, 0);
                }
        }
        __syncthreads();
    }

    unsigned short* Hseg = H + (size_t)e * T_TOK * INTERI;
#pragma unroll
    for (int i = 0; i < 4; ++i) {
        int rbase = m0 + wr + i * 16 + quad * 4;
#pragma unroll
        for (int r = 0; r < 4; ++r) {
            int row = rbase + r;
            if (row >= n_e) continue;
            unsigned short* hrow = Hseg + (size_t)row * INTERI + n0 + wc + lrow;
#pragma unroll
            for (int j = 0; j < 2; ++j) {
                float v1 = acc1[i][j][r];
                float v3 = acc3[i][j][r];
                float hv = (v1 / (1.f + __expf(-v1))) * v3;   // silu(v1)*v3
                hrow[j * 16] = f2b(hv);
            }
        }
    }
}

// ---------- GEMM2: y += w * (H W2^T), 128x64 tile, BK=64, pipelined ----------
__global__ __launch_bounds__(256) void gemm2_kernel(
    const unsigned short* __restrict__ H,
    const unsigned short* __restrict__ w2b,
    const unsigned short* __restrict__ ws2b,
    const int* __restrict__ counts,
    const int* __restrict__ lst,
    const float* __restrict__ lstw,
    float* __restrict__ y)
{
    const int e   = blockIdx.z;
    const int n_e = (e == NEXP) ? T_TOK : counts[e];
    const int m0  = blockIdx.x * 128;
    if (m0 >= n_e) return;
    const int n0  = blockIdx.y * 64;

    const unsigned short* w2p  = (e == NEXP) ? ws2b : w2b + (size_t)e * DIMD * INTERI;
    const unsigned short* Hseg = H + (size_t)e * T_TOK * INTERI;

    __shared__ __align__(16) unsigned short lA[2][2][128 * 32];  // 32 KB
    __shared__ __align__(16) unsigned short lB[2][2][64 * 32];   // 16 KB

    const int tid  = threadIdx.x;
    const int wave = tid >> 6;
    const int lane = tid & 63;
    const int r4   = tid >> 2;
    const int seg  = (tid & 3) * 8;

    int ra0 = m0 + r4;        if (ra0 > n_e - 1) ra0 = n_e - 1;
    int ra1 = m0 + r4 + 64;   if (ra1 > n_e - 1) ra1 = n_e - 1;

    const unsigned short* gA0 = Hseg + (size_t)ra0 * INTERI + seg;
    const unsigned short* gA1 = Hseg + (size_t)ra1 * INTERI + seg;
    const unsigned short* gB  = w2p + (size_t)(n0 + r4) * INTERI + seg;

    const int wbase = wave * 16 * 32;

    auto stage = [&](int k0, int b) {
#pragma unroll
        for (int kk = 0; kk < 2; ++kk) {
            cp16(gA0 + k0 + kk * 32, &lA[b][kk][wbase]);
            cp16(gA1 + k0 + kk * 32, &lA[b][kk][64 * 32 + wbase]);
            cp16(gB  + k0 + kk * 32, &lB[b][kk][wbase]);
        }
    };

    f32x4 acc[4][2];
    const f32x4 zero = {0.f, 0.f, 0.f, 0.f};
#pragma unroll
    for (int i = 0; i < 4; ++i)
#pragma unroll
        for (int j = 0; j < 2; ++j) acc[i][j] = zero;

    const int wr   = (wave >> 1) * 64;
    const int wc   = (wave & 1) * 32;
    const int quad = lane >> 4;
    const int lrow = lane & 15;

    stage(0, 0);
    __syncthreads();

    const int NK = INTERI / 64;  // 8
    for (int it = 0; it < NK; ++it) {
        const int b = it & 1;
        if (it + 1 < NK) stage((it + 1) * 64, b ^ 1);
#pragma unroll
        for (int kk = 0; kk < 2; ++kk) {
            bf16x8 a[4], bv[2];
#pragma unroll
            for (int t = 0; t < 4; ++t)
                a[t] = *(const bf16x8*)&lA[b][kk][(wr + t * 16 + lrow) * 32 + quad * 8];
#pragma unroll
            for (int t = 0; t < 2; ++t)
                bv[t] = *(const bf16x8*)&lB[b][kk][(wc + t * 16 + lrow) * 32 + quad * 8];
#pragma unroll
            for (int i = 0; i < 4; ++i)
#pragma unroll
                for (int j = 0; j < 2; ++j)
                    acc[i][j] = __builtin_amdgcn_mfma_f32_16x16x32_bf16(a[i], bv[j], acc[i][j], 0, 0, 0);
        }
        __syncthreads();
    }

#pragma unroll
    for (int i = 0; i < 4; ++i) {
        int rbase = m0 + wr + i * 16 + quad * 4;
#pragma unroll
        for (int r = 0; r < 4; ++r) {
            int row = rbase + r;
            if (row >= n_e) continue;
            int tok; float wt;
            if (e == NEXP) { tok = row; wt = 1.f; }
            else { tok = lst[e * T_TOK + row]; wt = lstw[e * T_TOK + row]; }
            float* yrow = y + (size_t)tok * DIMD + n0 + wc + lrow;
#pragma unroll
            for (int j = 0; j < 2; ++j)
                atomicAdd(&yrow[j * 16], wt * acc[i][j][r]);
        }
    }
}

// ---------- launcher ----------
extern "C" void kernel_launch(void* const* d_in, const int* in_sizes, int n_in,
                              void* d_out, int out_size, void* d_ws, size_t ws_size,
                              hipStream_t stream)
{
    const float* x   = (const float*)d_in[0];
    const float* gw  = (const float*)d_in[1];
    const float* gb  = (const float*)d_in[2];
    const float* w1  = (const float*)d_in[3];
    const float* w2  = (const float*)d_in[4];
    const float* w3  = (const float*)d_in[5];
    const float* ws1 = (const float*)d_in[6];
    const float* ws2 = (const float*)d_in[7];
    const float* ws3 = (const float*)d_in[8];

    char* base = (char*)d_ws;
    size_t off = 0;
    auto alloc = [&](size_t bytes) {
        char* q = base + off; off += (bytes + 255) & ~(size_t)255; return q;
    };
    unsigned short* xb   = (unsigned short*)alloc((size_t)T_TOK * DIMD * 2);
    unsigned short* w1b  = (unsigned short*)alloc((size_t)NEXP * INTERI * DIMD * 2);
    unsigned short* w3b  = (unsigned short*)alloc((size_t)NEXP * INTERI * DIMD * 2);
    unsigned short* w2b  = (unsigned short*)alloc((size_t)NEXP * DIMD * INTERI * 2);
    unsigned short* ws1b = (unsigned short*)alloc((size_t)INTERI * DIMD * 2);
    unsigned short* ws3b = (unsigned short*)alloc((size_t)INTERI * DIMD * 2);
    unsigned short* ws2b = (unsigned short*)alloc((size_t)DIMD * INTERI * 2);
    unsigned short* Hb   = (unsigned short*)alloc((size_t)NSEG * T_TOK * INTERI * 2);
    int*            cnts = (int*)alloc(NEXP * 4);
    int*            lstp = (int*)alloc((size_t)NEXP * T_TOK * 4);
    float*          lstw = (float*)alloc((size_t)NEXP * T_TOK * 4);

    hipMemsetAsync(cnts, 0, NEXP * 4, stream);
    hipMemsetAsync(d_out, 0, (size_t)T_TOK * DIMD * 4, stream);

    cvt_all_kernel<<<28160, 256, 0, stream>>>(x, w1, w3, w2, ws1, ws3, ws2,
                                              xb, w1b, w3b, w2b, ws1b, ws3b, ws2b);
    gate_kernel<<<T_TOK / 4, 256, 0, stream>>>(x, gw, gb, cnts, lstp, lstw);
    gemm1_kernel<<<dim3(16, 8, NSEG), 256, 0, stream>>>(xb, w1b, w3b, ws1b, ws3b, cnts, lstp, Hb);
    gemm2_kernel<<<dim3(16, 16, NSEG), 256, 0, stream>>>(Hb, w2b, ws2b, cnts, lstp, lstw, (float*)d_out);
}